// Round 7
// baseline (692.449 us; speedup 1.0000x reference)
//
#include <hip/hip_runtime.h>

#define C 128        // IN_CH == OUT_CH
#define NPB 16       // nodes per node-pre block
#define CAP 128      // per-node LDS bucket capacity (mean deg 64, 8 sigma; overflow path exists)
#define OVF_MAX 65536
#define EPT1 16      // edges per thread in partition kernel (block covers 4096 edges)
                     // 157 partition blocks: partition is parallelism-limited (r6: 40 blk = +8us)
#define GSH 4        // log2(nodes per bin)
#define G (1 << GSH) // 16 nodes per bin
#define CAPB 2048    // bin capacity (mean ~1024 + 157-run pad ~550 + 8 sigma; ovf path)
#define MAXBIN 1024  // static LDS sizing; requires NBIN <= MAXBIN (N <= 16384)
#define BCS 16       // bin_cursor stride in ints: one counter per 64B line

__device__ __forceinline__ unsigned bf16_bits(float x) {   // round-to-nearest-even
    unsigned u = __float_as_uint(x);
    u += 0x7FFFu + ((u >> 16) & 1u);
    return u >> 16;
}

// Heterogeneous kernel: blocks [0, PBLK) partition edges into coarse bins (16
// nodes/bin) with LDS histograms + 64B-aligned per-block runs (coalesced,
// XCD-private line ownership -> no partial-line write amplification).
// Blocks [PBLK, PBLK+PB) compute P = x@W1[:C] (bf16), Q = x@W1[C:] (fp32).
__global__ void fused_pre_kernel(const float* __restrict__ x, const float* __restrict__ W1,
                                 unsigned short* __restrict__ P16, float* __restrict__ Q,
                                 const int* __restrict__ ei, const float* __restrict__ attr,
                                 uint2* __restrict__ bins, int* __restrict__ bin_cursor,
                                 int* __restrict__ ovf_cnt, int2* __restrict__ ovf,
                                 int N, int E, int PBLK, int NBIN) {
    if ((int)blockIdx.x < PBLK) {
        __shared__ int hist[MAXBIN];   // pass1: counts; after reserve: global run base
        __shared__ int boff[MAXBIN];   // pass2: running offset within this block's run
        for (int i = threadIdx.x; i < NBIN; i += 256) { hist[i] = 0; boff[i] = 0; }
        __syncthreads();
        const int base = ((int)blockIdx.x * 256 + (int)threadIdx.x) * EPT1;
        const int rem = (base < E) ? min(EPT1, E - base) : 0;
        const bool vec = (rem == EPT1) && ((E & 3) == 0);
        // ---- pass 1: LDS histogram of destination bins ----
        if (vec) {
#pragma unroll
            for (int j0 = 0; j0 < EPT1; j0 += 4) {
                const int4 c = *(const int4*)(ei + (size_t)E + base + j0);
                atomicAdd(&hist[c.x >> GSH], 1);
                atomicAdd(&hist[c.y >> GSH], 1);
                atomicAdd(&hist[c.z >> GSH], 1);
                atomicAdd(&hist[c.w >> GSH], 1);
            }
        } else {
            for (int j = 0; j < rem; ++j)
                atomicAdd(&hist[ei[(size_t)E + base + j] >> GSH], 1);
        }
        __syncthreads();
        // ---- reserve a 64B-aligned run per bin; sentinel-fill the pad ----
        for (int i = threadIdx.x; i < NBIN; i += 256) {
            const int c = hist[i];
            int b = 0;
            if (c) {
                const int cp = (c + 7) & ~7;           // pad to 8 entries = 64B
                b = atomicAdd(&bin_cursor[i * BCS], cp);
                for (int k = c; k < cp; ++k)
                    if (b + k < CAPB)
                        bins[(size_t)i * CAPB + b + k] = make_uint2(0u, 0xFFFFFFFFu);
            }
            hist[i] = b;                               // repurpose as run base
        }
        __syncthreads();
        // ---- pass 2: place edges into the block's private runs ----
        if (vec) {
#pragma unroll
            for (int j0 = 0; j0 < EPT1; j0 += 4) {
                const int4 r = *(const int4*)(ei + base + j0);
                const int4 c = *(const int4*)(ei + (size_t)E + base + j0);
                const float4 a = *(const float4*)(attr + base + j0);
                const int rr[4] = {r.x, r.y, r.z, r.w};
                const int cc[4] = {c.x, c.y, c.z, c.w};
                const float aa[4] = {a.x, a.y, a.z, a.w};
#pragma unroll
                for (int j = 0; j < 4; ++j) {
                    const int bin = cc[j] >> GSH;
                    const int idx = hist[bin] + atomicAdd(&boff[bin], 1);
                    const unsigned pk = (bf16_bits(aa[j]) << 16) | (unsigned)rr[j];
                    if (idx < CAPB) {
                        bins[(size_t)bin * CAPB + idx] = make_uint2(pk, (unsigned)cc[j]);
                    } else {
                        const int o = atomicAdd(ovf_cnt, 1);
                        if (o < OVF_MAX) ovf[o] = make_int2(cc[j], (int)pk);
                    }
                }
            }
        } else {
            for (int j = 0; j < rem; ++j) {
                const int row = ei[base + j], colv = ei[(size_t)E + base + j];
                const int bin = colv >> GSH;
                const int idx = hist[bin] + atomicAdd(&boff[bin], 1);
                const unsigned pk = (bf16_bits(attr[base + j]) << 16) | (unsigned)row;
                if (idx < CAPB) {
                    bins[(size_t)bin * CAPB + idx] = make_uint2(pk, (unsigned)colv);
                } else {
                    const int o = atomicAdd(ovf_cnt, 1);
                    if (o < OVF_MAX) ovf[o] = make_int2(colv, (int)pk);
                }
            }
        }
    } else {
        // node pre-GEMM: 16 nodes/block, 256 threads. Thread = (node-group jg,
        // col-group col4): 4 nodes x 4 consecutive cols of the 256-wide [P|Q].
        __shared__ float xs[NPB][C];
        const int pb = (int)blockIdx.x - PBLK;
        const int n0 = pb * NPB;
        for (int i = threadIdx.x; i < NPB * C; i += 256) {
            const int gi = n0 * C + i;
            xs[0][i] = (gi < N * C) ? x[gi] : 0.f;
        }
        __syncthreads();
        const int col4 = threadIdx.x & 63;             // 64 col-groups
        const int jg   = threadIdx.x >> 6;             // wave index = node group
        const bool isQ = col4 >= 32;
        const int c0   = (isQ ? (col4 - 32) : col4) << 2;
        const float* __restrict__ Wb = W1 + (isQ ? (C * C) : 0) + c0;
        float acc[4][4] = {};
        for (int k = 0; k < C; k += 4) {
            const float4 w0 = *(const float4*)(Wb + (size_t)(k + 0) * C);
            const float4 w1 = *(const float4*)(Wb + (size_t)(k + 1) * C);
            const float4 w2 = *(const float4*)(Wb + (size_t)(k + 2) * C);
            const float4 w3 = *(const float4*)(Wb + (size_t)(k + 3) * C);
#pragma unroll
            for (int j = 0; j < 4; ++j) {
                const float4 xv = *(const float4*)(&xs[jg * 4 + j][k]);   // broadcast b128
                acc[j][0] = fmaf(xv.x, w0.x, fmaf(xv.y, w1.x, fmaf(xv.z, w2.x, fmaf(xv.w, w3.x, acc[j][0]))));
                acc[j][1] = fmaf(xv.x, w0.y, fmaf(xv.y, w1.y, fmaf(xv.z, w2.y, fmaf(xv.w, w3.y, acc[j][1]))));
                acc[j][2] = fmaf(xv.x, w0.z, fmaf(xv.y, w1.z, fmaf(xv.z, w2.z, fmaf(xv.w, w3.z, acc[j][2]))));
                acc[j][3] = fmaf(xv.x, w0.w, fmaf(xv.y, w1.w, fmaf(xv.z, w2.w, fmaf(xv.w, w3.w, acc[j][3]))));
            }
        }
#pragma unroll
        for (int j = 0; j < 4; ++j) {
            const int n = n0 + jg * 4 + j;
            if (n < N) {
                if (isQ) {
                    *(float4*)(Q + (size_t)n * C + c0) =
                        make_float4(acc[j][0], acc[j][1], acc[j][2], acc[j][3]);
                } else {
                    ushort4 s;
                    s.x = (unsigned short)bf16_bits(acc[j][0]);
                    s.y = (unsigned short)bf16_bits(acc[j][1]);
                    s.z = (unsigned short)bf16_bits(acc[j][2]);
                    s.w = (unsigned short)bf16_bits(acc[j][3]);
                    *(ushort4*)(P16 + (size_t)n * C + c0) = s;
                }
            }
        }
    }
}

// Merged scatter + aggregation + output GEMM. One block per bin (16 nodes),
// 512 threads (8 waves): ~20 waves/CU at 625 blocks -> 2x latency hiding for
// the gather phase vs the 256-thread version (~10 waves/CU).
// Phase 1: stream bin entries (coalesced) into per-node LDS buckets.
// Phase 2: 32 lanes x 4 channels per node; 4-deep-ILP uint2 P16 gathers;
//          H = sum relu(a*P + Q + b1) in registers, written into the SAME LDS
//          (bucket row g is dead once group g finishes reading it).
// Phase 3: out = H @ W2 + deg*b2 from the LDS H tile (broadcast float4 reads).
// ovf correctness: entries for node n are appended only by K1 (pre-launch) or
// by n's own block before its barrier -> visible to the scan that needs them.
__global__ void bin_agg_out_kernel(const uint2* __restrict__ bins, const int* __restrict__ bin_cursor,
                                   const unsigned short* __restrict__ P16, const float* __restrict__ Q,
                                   const float* __restrict__ b1, const float* __restrict__ W2,
                                   const float* __restrict__ b2,
                                   int* __restrict__ ovf_cnt, int2* __restrict__ ovf,
                                   float* __restrict__ out, int N) {
    __shared__ unsigned smem[G][C];   // phase1/2: buckets; phase3: H tile (floats)
    __shared__ int off[G];
    float* __restrict__ smemf = (float*)&smem[0][0];
    const int t = threadIdx.x;
    const int b = blockIdx.x;
    const int n0 = b << GSH;
    if (t < G) off[t] = 0;
    __syncthreads();
    // ---- phase 1: bin -> per-node LDS buckets ----
    const int cnt = min(bin_cursor[b * BCS], CAPB);
    const uint2* __restrict__ src = bins + (size_t)b * CAPB;
    for (int i = t; i < cnt; i += 512) {
        const uint2 e = src[i];
        const unsigned noff = e.y - (unsigned)n0;
        if (noff < (unsigned)G) {                      // skip run-pad sentinels
            const int pos = atomicAdd(&off[noff], 1);
            if (pos < CAP) {
                smem[noff][pos] = e.x;
            } else {
                const int o = atomicAdd(ovf_cnt, 1);
                if (o < OVF_MAX) ovf[o] = make_int2((int)e.y, (int)e.x);
            }
        }
    }
    __syncthreads();
    // ---- phase 2: per-node aggregation, 32 lanes x 4 channels ----
    const int g = t >> 5;
    const int ch4 = t & 31;
    const int n = n0 + g;
#define PROC(ew, p, qb)                                                                  \
    {                                                                                    \
        const float a_ = __uint_as_float((ew) & 0xFFFF0000u);                            \
        acc.x += fmaxf(fmaf(a_, __uint_as_float((p).x << 16),         qb.x), 0.f);       \
        acc.y += fmaxf(fmaf(a_, __uint_as_float((p).x & 0xFFFF0000u), qb.y), 0.f);       \
        acc.z += fmaxf(fmaf(a_, __uint_as_float((p).y << 16),         qb.z), 0.f);       \
        acc.w += fmaxf(fmaf(a_, __uint_as_float((p).y & 0xFFFF0000u), qb.w), 0.f);       \
    }
    float4 acc = make_float4(0.f, 0.f, 0.f, 0.f);
    int degp = 0, mcnt = 0;
    if (n < N) {
        degp = min(off[g], CAP);
        const float4 q4  = *(const float4*)(Q + (size_t)n * C + (ch4 << 2));
        const float4 b14 = *(const float4*)(b1 + (ch4 << 2));
        const float4 qb = make_float4(q4.x + b14.x, q4.y + b14.y, q4.z + b14.z, q4.w + b14.w);
        int i = 0;
        for (; i + 4 <= degp; i += 4) {
            const uint4 e4 = *(const uint4*)(&smem[g][i]);   // broadcast: 4 edges
            const uint2 p0 = *(const uint2*)(P16 + (((size_t)(e4.x & 0xFFFFu)) << 7) + (ch4 << 2));
            const uint2 p1 = *(const uint2*)(P16 + (((size_t)(e4.y & 0xFFFFu)) << 7) + (ch4 << 2));
            const uint2 p2 = *(const uint2*)(P16 + (((size_t)(e4.z & 0xFFFFu)) << 7) + (ch4 << 2));
            const uint2 p3 = *(const uint2*)(P16 + (((size_t)(e4.w & 0xFFFFu)) << 7) + (ch4 << 2));
            PROC(e4.x, p0, qb);
            PROC(e4.y, p1, qb);
            PROC(e4.z, p2, qb);
            PROC(e4.w, p3, qb);
        }
        for (; i < degp; ++i) {
            const unsigned ew = smem[g][i];
            const uint2 p = *(const uint2*)(P16 + (((size_t)(ew & 0xFFFFu)) << 7) + (ch4 << 2));
            PROC(ew, p, qb);
        }
        // overflow entries (essentially never populated)
        const int oc = min(*ovf_cnt, OVF_MAX);
        for (int o = 0; o < oc; ++o) {
            const int2 v = ovf[o];
            if (v.x == n) {
                ++mcnt;
                const unsigned ew = (unsigned)v.y;
                const uint2 p = *(const uint2*)(P16 + (((size_t)(ew & 0xFFFFu)) << 7) + (ch4 << 2));
                PROC(ew, p, qb);
            }
        }
        // bucket row g fully consumed -> overwrite in place with H row g
        *(float4*)(smemf + g * C + (ch4 << 2)) = acc;
        if (ch4 == 0) off[g] = degp + mcnt;            // final degree for b2 term
    }
#undef PROC
    __syncthreads();
    // ---- phase 3: out = H @ W2 + deg*b2 (4 nodes per quarter, broadcast b128) ----
    const int col = t & (C - 1);
    const int sub = t >> 7;                            // 0..3
    float acc3[4] = {};
    for (int k = 0; k < C; k += 4) {
        const float w0 = W2[(k + 0) * C + col];
        const float w1 = W2[(k + 1) * C + col];
        const float w2v = W2[(k + 2) * C + col];
        const float w3 = W2[(k + 3) * C + col];
#pragma unroll
        for (int j = 0; j < 4; ++j) {
            const float4 h4 = *(const float4*)(smemf + (sub * 4 + j) * C + k);
            acc3[j] = fmaf(h4.x, w0, fmaf(h4.y, w1, fmaf(h4.z, w2v, fmaf(h4.w, w3, acc3[j]))));
        }
    }
    const float bv = b2[col];
#pragma unroll
    for (int j = 0; j < 4; ++j) {
        const int n2 = n0 + sub * 4 + j;
        if (n2 < N) out[(size_t)n2 * C + col] = fmaf((float)off[sub * 4 + j], bv, acc3[j]);
    }
}

extern "C" void kernel_launch(void* const* d_in, const int* in_sizes, int n_in,
                              void* d_out, int out_size, void* d_ws, size_t ws_size,
                              hipStream_t stream) {
    const float* x    = (const float*)d_in[0];
    const int*   ei   = (const int*)d_in[1];
    const float* attr = (const float*)d_in[2];
    const float* W1   = (const float*)d_in[3];
    const float* b1   = (const float*)d_in[4];
    const float* W2   = (const float*)d_in[5];
    const float* b2   = (const float*)d_in[6];
    float* out = (float*)d_out;

    const int N = in_sizes[0] / C;
    const int E = in_sizes[2];
    const int NBIN = (N + G - 1) >> GSH;   // 625 for N=10000; must be <= MAXBIN

    char* ws = (char*)d_ws;
    unsigned short* P16 = (unsigned short*)ws;  ws += (size_t)N * C * sizeof(unsigned short);
    ws = (char*)(((uintptr_t)ws + 15) & ~(uintptr_t)15);
    float*    Q       = (float*)ws;     ws += (size_t)N * C * sizeof(float);
    uint2*    bins    = (uint2*)ws;     ws += (size_t)NBIN * CAPB * sizeof(uint2);
    int2*     ovf     = (int2*)ws;      ws += (size_t)OVF_MAX * sizeof(int2);
    int*      bin_cursor = (int*)ws;    ws += (size_t)NBIN * BCS * sizeof(int);
    int*      ovf_cnt = (int*)ws;       // adjacent to bin_cursor -> single memset

    hipMemsetAsync(bin_cursor, 0, ((size_t)NBIN * BCS + 1) * sizeof(int), stream);

    const int PBLK = (E + 256 * EPT1 - 1) / (256 * EPT1);   // 157 partition blocks
    const int PB = (N + NPB - 1) / NPB;                     // 625 pre-GEMM blocks
    fused_pre_kernel<<<PBLK + PB, 256, 0, stream>>>(x, W1, P16, Q, ei, attr,
                                                    bins, bin_cursor, ovf_cnt, ovf,
                                                    N, E, PBLK, NBIN);
    bin_agg_out_kernel<<<NBIN, 512, 0, stream>>>(bins, bin_cursor, P16, Q, b1, W2, b2,
                                                 ovf_cnt, ovf, out, N);
}

// Round 8
// 132.483 us; speedup vs baseline: 5.2267x; 5.2267x over previous
//
#include <hip/hip_runtime.h>

#define C 128        // IN_CH == OUT_CH
#define NPB 16       // nodes per node-pre block
#define CAP 128      // per-node LDS bucket capacity (mean deg 64, 8 sigma; overflow path exists)
#define OVF_MAX 65536
#define EPT1 16      // edges per thread in partition kernel (block covers 4096 edges)
                     // 157 blocks: partition is parallelism-limited (r6: 40 blk = +8us)
#define GSH 4        // log2(nodes per bin)
#define G (1 << GSH) // 16 nodes per bin
#define CAPB 2048    // bin capacity (mean fill ~1515 with 157 runs' pad, 12 sigma; ovf path)
#define MAXBIN 1024  // static LDS sizing; requires NBIN <= MAXBIN (N <= 16384)
#define BCS 16       // bin_cursor stride in ints: one counter per 64B line

// LESSON (r5/r7): P16 gathers MUST be uint4 (16 B/lane, 16 lanes x 8ch per node).
// Both rounds that used uint2 (8 B/lane, 32 lanes x 4ch) -- with otherwise
// unrelated structures -- blew up 15x with ~1 GB HBM traffic. Do not narrow
// the gather width again.

__device__ __forceinline__ unsigned bf16_bits(float x) {   // round-to-nearest-even
    unsigned u = __float_as_uint(x);
    u += 0x7FFFu + ((u >> 16) & 1u);
    return u >> 16;
}

// Heterogeneous kernel: blocks [0, PBLK) partition edges into coarse bins (16
// nodes/bin) with LDS histograms + 64B-aligned per-block runs (coalesced,
// XCD-private line ownership -> no partial-line write amplification).
// Blocks [PBLK, PBLK+PB) compute P = x@W1[:C] (bf16), Q = x@W1[C:] (fp32).
__global__ void fused_pre_kernel(const float* __restrict__ x, const float* __restrict__ W1,
                                 unsigned short* __restrict__ P16, float* __restrict__ Q,
                                 const int* __restrict__ ei, const float* __restrict__ attr,
                                 uint2* __restrict__ bins, int* __restrict__ bin_cursor,
                                 int* __restrict__ ovf_cnt, int2* __restrict__ ovf,
                                 int N, int E, int PBLK, int NBIN) {
    if ((int)blockIdx.x < PBLK) {
        __shared__ int hist[MAXBIN];   // pass1: counts; after reserve: global run base
        __shared__ int boff[MAXBIN];   // pass2: running offset within this block's run
        for (int i = threadIdx.x; i < NBIN; i += 256) { hist[i] = 0; boff[i] = 0; }
        __syncthreads();
        const int base = ((int)blockIdx.x * 256 + (int)threadIdx.x) * EPT1;
        const int rem = (base < E) ? min(EPT1, E - base) : 0;
        const bool vec = (rem == EPT1) && ((E & 3) == 0);
        // ---- pass 1: LDS histogram of destination bins ----
        if (vec) {
#pragma unroll
            for (int j0 = 0; j0 < EPT1; j0 += 4) {
                const int4 c = *(const int4*)(ei + (size_t)E + base + j0);
                atomicAdd(&hist[c.x >> GSH], 1);
                atomicAdd(&hist[c.y >> GSH], 1);
                atomicAdd(&hist[c.z >> GSH], 1);
                atomicAdd(&hist[c.w >> GSH], 1);
            }
        } else {
            for (int j = 0; j < rem; ++j)
                atomicAdd(&hist[ei[(size_t)E + base + j] >> GSH], 1);
        }
        __syncthreads();
        // ---- reserve a 64B-aligned run per bin; sentinel-fill the pad ----
        for (int i = threadIdx.x; i < NBIN; i += 256) {
            const int c = hist[i];
            int b = 0;
            if (c) {
                const int cp = (c + 7) & ~7;           // pad to 8 entries = 64B
                b = atomicAdd(&bin_cursor[i * BCS], cp);
                for (int k = c; k < cp; ++k)
                    if (b + k < CAPB)
                        bins[(size_t)i * CAPB + b + k] = make_uint2(0u, 0xFFFFFFFFu);
            }
            hist[i] = b;                               // repurpose as run base
        }
        __syncthreads();
        // ---- pass 2: place edges into the block's private runs ----
        if (vec) {
#pragma unroll
            for (int j0 = 0; j0 < EPT1; j0 += 4) {
                const int4 r = *(const int4*)(ei + base + j0);
                const int4 c = *(const int4*)(ei + (size_t)E + base + j0);
                const float4 a = *(const float4*)(attr + base + j0);
                const int rr[4] = {r.x, r.y, r.z, r.w};
                const int cc[4] = {c.x, c.y, c.z, c.w};
                const float aa[4] = {a.x, a.y, a.z, a.w};
#pragma unroll
                for (int j = 0; j < 4; ++j) {
                    const int bin = cc[j] >> GSH;
                    const int idx = hist[bin] + atomicAdd(&boff[bin], 1);
                    const unsigned pk = (bf16_bits(aa[j]) << 16) | (unsigned)rr[j];
                    if (idx < CAPB) {
                        bins[(size_t)bin * CAPB + idx] = make_uint2(pk, (unsigned)cc[j]);
                    } else {
                        const int o = atomicAdd(ovf_cnt, 1);
                        if (o < OVF_MAX) ovf[o] = make_int2(cc[j], (int)pk);
                    }
                }
            }
        } else {
            for (int j = 0; j < rem; ++j) {
                const int row = ei[base + j], colv = ei[(size_t)E + base + j];
                const int bin = colv >> GSH;
                const int idx = hist[bin] + atomicAdd(&boff[bin], 1);
                const unsigned pk = (bf16_bits(attr[base + j]) << 16) | (unsigned)row;
                if (idx < CAPB) {
                    bins[(size_t)bin * CAPB + idx] = make_uint2(pk, (unsigned)colv);
                } else {
                    const int o = atomicAdd(ovf_cnt, 1);
                    if (o < OVF_MAX) ovf[o] = make_int2(colv, (int)pk);
                }
            }
        }
    } else {
        // node pre-GEMM: 16 nodes/block, 256 threads. Thread = (node-group jg,
        // col-group col4): 4 nodes x 4 consecutive cols of the 256-wide [P|Q].
        __shared__ float xs[NPB][C];
        const int pb = (int)blockIdx.x - PBLK;
        const int n0 = pb * NPB;
        for (int i = threadIdx.x; i < NPB * C; i += 256) {
            const int gi = n0 * C + i;
            xs[0][i] = (gi < N * C) ? x[gi] : 0.f;
        }
        __syncthreads();
        const int col4 = threadIdx.x & 63;             // 64 col-groups
        const int jg   = threadIdx.x >> 6;             // wave index = node group
        const bool isQ = col4 >= 32;
        const int c0   = (isQ ? (col4 - 32) : col4) << 2;
        const float* __restrict__ Wb = W1 + (isQ ? (C * C) : 0) + c0;
        float acc[4][4] = {};
        for (int k = 0; k < C; k += 4) {
            const float4 w0 = *(const float4*)(Wb + (size_t)(k + 0) * C);
            const float4 w1 = *(const float4*)(Wb + (size_t)(k + 1) * C);
            const float4 w2 = *(const float4*)(Wb + (size_t)(k + 2) * C);
            const float4 w3 = *(const float4*)(Wb + (size_t)(k + 3) * C);
#pragma unroll
            for (int j = 0; j < 4; ++j) {
                const float4 xv = *(const float4*)(&xs[jg * 4 + j][k]);   // broadcast b128
                acc[j][0] = fmaf(xv.x, w0.x, fmaf(xv.y, w1.x, fmaf(xv.z, w2.x, fmaf(xv.w, w3.x, acc[j][0]))));
                acc[j][1] = fmaf(xv.x, w0.y, fmaf(xv.y, w1.y, fmaf(xv.z, w2.y, fmaf(xv.w, w3.y, acc[j][1]))));
                acc[j][2] = fmaf(xv.x, w0.z, fmaf(xv.y, w1.z, fmaf(xv.z, w2.z, fmaf(xv.w, w3.z, acc[j][2]))));
                acc[j][3] = fmaf(xv.x, w0.w, fmaf(xv.y, w1.w, fmaf(xv.z, w2.w, fmaf(xv.w, w3.w, acc[j][3]))));
            }
        }
#pragma unroll
        for (int j = 0; j < 4; ++j) {
            const int n = n0 + jg * 4 + j;
            if (n < N) {
                if (isQ) {
                    *(float4*)(Q + (size_t)n * C + c0) =
                        make_float4(acc[j][0], acc[j][1], acc[j][2], acc[j][3]);
                } else {
                    ushort4 s;
                    s.x = (unsigned short)bf16_bits(acc[j][0]);
                    s.y = (unsigned short)bf16_bits(acc[j][1]);
                    s.z = (unsigned short)bf16_bits(acc[j][2]);
                    s.w = (unsigned short)bf16_bits(acc[j][3]);
                    *(ushort4*)(P16 + (size_t)n * C + c0) = s;
                }
            }
        }
    }
}

// Merged scatter + aggregation + output GEMM. One block per bin (16 nodes),
// 256 threads. (r4-verified structure; r7's 512-thread/uint2 variant = 15x slower.)
// Phase 1: stream bin entries (coalesced) into per-node LDS buckets.
// Phase 2: one 16-lane group per node; each lane owns 8 channels; 4-deep-ILP
//          uint4 P16 gathers; H = sum relu(a*P + Q + b1) accumulated fully in
//          registers, then written into the SAME LDS (bucket row g is dead
//          once group g finishes reading it).
// Phase 3: out = H @ W2 + deg*b2 from the LDS H tile (float4 ds reads).
// ovf correctness: entries for node n are appended only by K1 (pre-launch) or
// by n's own block before its barrier -> visible to the scan that needs them.
__global__ void bin_agg_out_kernel(const uint2* __restrict__ bins, const int* __restrict__ bin_cursor,
                                   const unsigned short* __restrict__ P16, const float* __restrict__ Q,
                                   const float* __restrict__ b1, const float* __restrict__ W2,
                                   const float* __restrict__ b2,
                                   int* __restrict__ ovf_cnt, int2* __restrict__ ovf,
                                   float* __restrict__ out, int N) {
    __shared__ unsigned smem[G][C];   // phase1/2: buckets; phase3: H tile (floats)
    __shared__ int off[G];
    float* __restrict__ smemf = (float*)&smem[0][0];
    const int t = threadIdx.x;
    const int b = blockIdx.x;
    const int n0 = b << GSH;
    if (t < G) off[t] = 0;
    __syncthreads();
    // ---- phase 1: bin -> per-node LDS buckets ----
    const int cnt = min(bin_cursor[b * BCS], CAPB);
    const uint2* __restrict__ src = bins + (size_t)b * CAPB;
    for (int i = t; i < cnt; i += 256) {
        const uint2 e = src[i];
        const unsigned noff = e.y - (unsigned)n0;
        if (noff < (unsigned)G) {                      // skip run-pad sentinels
            const int pos = atomicAdd(&off[noff], 1);
            if (pos < CAP) {
                smem[noff][pos] = e.x;
            } else {
                const int o = atomicAdd(ovf_cnt, 1);
                if (o < OVF_MAX) ovf[o] = make_int2((int)e.y, (int)e.x);
            }
        }
    }
    __syncthreads();
    // ---- phase 2: per-node aggregation, 16 lanes x 8 channels ----
    const int g = t >> 4;
    const int ch8 = t & 15;
    const int n = n0 + g;
#define PROC(ew, p, qb0, qb1)                                                            \
    {                                                                                    \
        const float a_ = __uint_as_float((ew) & 0xFFFF0000u);                            \
        acc0.x += fmaxf(fmaf(a_, __uint_as_float((p).x << 16),         qb0.x), 0.f);     \
        acc0.y += fmaxf(fmaf(a_, __uint_as_float((p).x & 0xFFFF0000u), qb0.y), 0.f);     \
        acc0.z += fmaxf(fmaf(a_, __uint_as_float((p).y << 16),         qb0.z), 0.f);     \
        acc0.w += fmaxf(fmaf(a_, __uint_as_float((p).y & 0xFFFF0000u), qb0.w), 0.f);     \
        acc1.x += fmaxf(fmaf(a_, __uint_as_float((p).z << 16),         qb1.x), 0.f);     \
        acc1.y += fmaxf(fmaf(a_, __uint_as_float((p).z & 0xFFFF0000u), qb1.y), 0.f);     \
        acc1.z += fmaxf(fmaf(a_, __uint_as_float((p).w << 16),         qb1.z), 0.f);     \
        acc1.w += fmaxf(fmaf(a_, __uint_as_float((p).w & 0xFFFF0000u), qb1.w), 0.f);     \
    }
    float4 acc0 = make_float4(0.f, 0.f, 0.f, 0.f);
    float4 acc1 = acc0;
    int degp = 0, mcnt = 0;
    if (n < N) {
        degp = min(off[g], CAP);
        const float4 qlo = *(const float4*)(Q + (size_t)n * C + (ch8 << 3));
        const float4 qhi = *(const float4*)(Q + (size_t)n * C + (ch8 << 3) + 4);
        const float4 blo = *(const float4*)(b1 + (ch8 << 3));
        const float4 bhi = *(const float4*)(b1 + (ch8 << 3) + 4);
        const float4 qb0 = make_float4(qlo.x + blo.x, qlo.y + blo.y, qlo.z + blo.z, qlo.w + blo.w);
        const float4 qb1 = make_float4(qhi.x + bhi.x, qhi.y + bhi.y, qhi.z + bhi.z, qhi.w + bhi.w);
        int i = 0;
        for (; i + 4 <= degp; i += 4) {
            const uint4 e4 = *(const uint4*)(&smem[g][i]);   // broadcast: 4 edges
            const uint4 p0 = *(const uint4*)(P16 + (((size_t)(e4.x & 0xFFFFu)) << 7) + (ch8 << 3));
            const uint4 p1 = *(const uint4*)(P16 + (((size_t)(e4.y & 0xFFFFu)) << 7) + (ch8 << 3));
            const uint4 p2 = *(const uint4*)(P16 + (((size_t)(e4.z & 0xFFFFu)) << 7) + (ch8 << 3));
            const uint4 p3 = *(const uint4*)(P16 + (((size_t)(e4.w & 0xFFFFu)) << 7) + (ch8 << 3));
            PROC(e4.x, p0, qb0, qb1);
            PROC(e4.y, p1, qb0, qb1);
            PROC(e4.z, p2, qb0, qb1);
            PROC(e4.w, p3, qb0, qb1);
        }
        for (; i < degp; ++i) {
            const unsigned ew = smem[g][i];
            const uint4 p = *(const uint4*)(P16 + (((size_t)(ew & 0xFFFFu)) << 7) + (ch8 << 3));
            PROC(ew, p, qb0, qb1);
        }
        // overflow entries (essentially never populated)
        const int oc = min(*ovf_cnt, OVF_MAX);
        for (int o = 0; o < oc; ++o) {
            const int2 v = ovf[o];
            if (v.x == n) {
                ++mcnt;
                const unsigned ew = (unsigned)v.y;
                const uint4 p = *(const uint4*)(P16 + (((size_t)(ew & 0xFFFFu)) << 7) + (ch8 << 3));
                PROC(ew, p, qb0, qb1);
            }
        }
        // bucket row g fully consumed -> overwrite in place with H row g
        *(float4*)(smemf + g * C + (ch8 << 3))     = acc0;
        *(float4*)(smemf + g * C + (ch8 << 3) + 4) = acc1;
        if (ch8 == 0) off[g] = degp + mcnt;            // final degree for b2 term
    }
#undef PROC
    __syncthreads();
    // ---- phase 3: out = H @ W2 + deg*b2 (8 nodes per half, float4 ds reads) ----
    const int col = t & (C - 1);
    const int half = t >> 7;
    float acc[8] = {};
    for (int k = 0; k < C; k += 4) {
        const float w0 = W2[(k + 0) * C + col];
        const float w1 = W2[(k + 1) * C + col];
        const float w2v = W2[(k + 2) * C + col];
        const float w3 = W2[(k + 3) * C + col];
#pragma unroll
        for (int j = 0; j < 8; ++j) {
            const float4 h4 = *(const float4*)(smemf + (half * 8 + j) * C + k);
            acc[j] = fmaf(h4.x, w0, fmaf(h4.y, w1, fmaf(h4.z, w2v, fmaf(h4.w, w3, acc[j]))));
        }
    }
    const float bv = b2[col];
#pragma unroll
    for (int j = 0; j < 8; ++j) {
        const int n2 = n0 + half * 8 + j;
        if (n2 < N) out[(size_t)n2 * C + col] = fmaf((float)off[half * 8 + j], bv, acc[j]);
    }
}

extern "C" void kernel_launch(void* const* d_in, const int* in_sizes, int n_in,
                              void* d_out, int out_size, void* d_ws, size_t ws_size,
                              hipStream_t stream) {
    const float* x    = (const float*)d_in[0];
    const int*   ei   = (const int*)d_in[1];
    const float* attr = (const float*)d_in[2];
    const float* W1   = (const float*)d_in[3];
    const float* b1   = (const float*)d_in[4];
    const float* W2   = (const float*)d_in[5];
    const float* b2   = (const float*)d_in[6];
    float* out = (float*)d_out;

    const int N = in_sizes[0] / C;
    const int E = in_sizes[2];
    const int NBIN = (N + G - 1) >> GSH;   // 625 for N=10000; must be <= MAXBIN

    char* ws = (char*)d_ws;
    unsigned short* P16 = (unsigned short*)ws;  ws += (size_t)N * C * sizeof(unsigned short);
    ws = (char*)(((uintptr_t)ws + 15) & ~(uintptr_t)15);
    float*    Q       = (float*)ws;     ws += (size_t)N * C * sizeof(float);
    uint2*    bins    = (uint2*)ws;     ws += (size_t)NBIN * CAPB * sizeof(uint2);
    int2*     ovf     = (int2*)ws;      ws += (size_t)OVF_MAX * sizeof(int2);
    int*      bin_cursor = (int*)ws;    ws += (size_t)NBIN * BCS * sizeof(int);
    int*      ovf_cnt = (int*)ws;       // adjacent to bin_cursor -> single memset

    hipMemsetAsync(bin_cursor, 0, ((size_t)NBIN * BCS + 1) * sizeof(int), stream);

    const int PBLK = (E + 256 * EPT1 - 1) / (256 * EPT1);   // 157 partition blocks
    const int PB = (N + NPB - 1) / NPB;                     // 625 pre-GEMM blocks
    fused_pre_kernel<<<PBLK + PB, 256, 0, stream>>>(x, W1, P16, Q, ei, attr,
                                                    bins, bin_cursor, ovf_cnt, ovf,
                                                    N, E, PBLK, NBIN);
    bin_agg_out_kernel<<<NBIN, 256, 0, stream>>>(bins, bin_cursor, P16, Q, b1, W2, b2,
                                                 ovf_cnt, ovf, out, N);
}